// Round 11
// baseline (223.943 us; speedup 1.0000x reference)
//
#include <hip/hip_runtime.h>
#include <hip/hip_bf16.h>

#define NROWS 8192
#define DIM 512
#define NSLOT 194  // per-row top-2 slots: 66 row-side + 128 col-side (32 s x 4 row-groups)
#define KMASK 0xFFFFE000u  // top-19 key bits; low 13 = index
#define QSCALE 21.0f       // i8 quantization scale: clamp +-6.05 (> global max ~5.2)
#define QD2 (-2.0f / (QSCALE * QSCALE))

typedef __attribute__((ext_vector_type(8))) short bf16x8;
typedef __attribute__((ext_vector_type(4))) float f32x4;
typedef __attribute__((ext_vector_type(4))) int i32x4;
typedef __attribute__((ext_vector_type(8))) unsigned short u16x8;

__device__ __forceinline__ float bf2f(unsigned short u) {
    return __uint_as_float(((unsigned int)u) << 16);
}
__device__ __forceinline__ unsigned short f2bf(float f) {
    unsigned int b = __float_as_uint(f);
    return (unsigned short)((b + 0x7FFFu + ((b >> 16) & 1u)) >> 16);
}
// fp32 -> signed i8, RNE, scale QSCALE (no clipping for N(0,1): 127/21=6.05 > max ~5.2)
__device__ __forceinline__ unsigned char f2i8(float x) {
    float s = x * QSCALE;
    s = fminf(fmaxf(s, -127.f), 127.f);
    const int q = __float2int_rn(s);
    return (unsigned char)(q & 0xFF);
}
// monotone float->uint key
__device__ __forceinline__ unsigned int fkey(float f) {
    unsigned int b = __float_as_uint(f);
    return (b & 0x80000000u) ? ~b : (b | 0x80000000u);
}
__device__ __forceinline__ float unfkey(unsigned int u) {
    unsigned int b = (u & 0x80000000u) ? (u ^ 0x80000000u) : ~u;
    return __uint_as_float(b);
}
__device__ __forceinline__ unsigned int minu(unsigned int a, unsigned int b) {
    return a < b ? a : b;
}
__device__ __forceinline__ unsigned int maxu(unsigned int a, unsigned int b) {
    return a > b ? a : b;
}
__device__ __forceinline__ unsigned long long min64(unsigned long long a,
                                                    unsigned long long b) {
    return a < b ? a : b;
}
// VALU-pipe lane broadcast (v_readlane, compile-time k) -- r7-proven DS-pipe fix.
__device__ __forceinline__ float bcastf(float v, int k) {
    return __uint_as_float((unsigned int)__builtin_amdgcn_readlane(__float_as_uint(v), k));
}

// helper: 3-way bf16 split
__device__ __forceinline__ void split3(const float* v, u16x8& h8, u16x8& m8, u16x8& l8) {
#pragma unroll
    for (int j = 0; j < 8; ++j) {
        const float x = v[j];
        const unsigned short h = f2bf(x);
        const float r1 = x - bf2f(h);
        const unsigned short m = f2bf(r1);
        const float r2 = r1 - bf2f(m);
        h8[j] = h; m8[j] = m; l8[j] = f2bf(r2);
    }
}
// helper: 2-way split
__device__ __forceinline__ void split2(const float* v, u16x8& h8, u16x8& l8) {
#pragma unroll
    for (int j = 0; j < 8; ++j) {
        const float x = v[j];
        const unsigned short h = f2bf(x);
        h8[j] = h; l8[j] = f2bf(x - bf2f(h));
    }
}

// ---------------------------------------------------------------- k_prep
// Prep ONLY (i8 plane + sq): 2048 blocks, HBM-bound (~20 MB traffic).
__global__ __launch_bounds__(256) void k_prep(const float* __restrict__ xs,
                                              unsigned char* __restrict__ x8,
                                              float* __restrict__ sq) {
    const int tid = threadIdx.x;
    const int wave = tid >> 6, lane = tid & 63;
    const int row = blockIdx.x * 4 + wave;
    const float4* xr = (const float4*)(xs + (size_t)row * DIM);
    const float4 a = xr[2 * lane], b = xr[2 * lane + 1];
    float v[8] = {a.x, a.y, a.z, a.w, b.x, b.y, b.z, b.w};
    unsigned long long pk8 = 0ull;
    float s = 0.f;
#pragma unroll
    for (int i = 0; i < 8; ++i) {
        pk8 |= ((unsigned long long)f2i8(v[i])) << (8 * i);
        s = fmaf(v[i], v[i], s);
    }
    *(unsigned long long*)(x8 + (size_t)row * DIM + lane * 8) = pk8;
#pragma unroll
    for (int d = 32; d; d >>= 1) s += __shfl_xor(s, d);
    if (lane == 0) sq[row] = s;
}

// ---------------------------------------------------------------- k_nn
// Blocks 0..127: P = xs @ W1^T (3-way-split bf16 MFMA, tid<256 guard).
// Blocks 128..2239: i8 candidate pass, MAIN LOOP NOW BARRIER- AND LDS-FREE:
// fragments load DIRECTLY from the L2-resident x8 plane (the LDS swizzle
// machinery provably delivered global bytes x8[(i0+r)*512+kt*64+quad*16] --
// store/read swizzles cancel -- so the round-trip was pure overhead: 6
// ds_read_b128/wave/kt on the one-per-CU DS pipe ~19us + 16 barrier drains).
// Fragment loads are 64B-line-aligned (quads 0..3 of a row share one line);
// A rows L2-hit across ~8 same-XCD blocks, B tile L1-hits its 4x reuse.
__global__ __launch_bounds__(512, 4) void k_nn(const unsigned char* __restrict__ x8,
                                               const float* __restrict__ sq,
                                               unsigned int* __restrict__ rowtab,
                                               const float* __restrict__ xs,
                                               const float* __restrict__ W1,
                                               float* __restrict__ P) {
    __shared__ __align__(16) unsigned char lsm[32768];
    const int tid = threadIdx.x;
    const int wave = tid >> 6, lane = tid & 63, quad = lane >> 4, ln = lane & 15;

    if (blockIdx.x < 128) {
        // ---- P-GEMM tile (256 active threads; all 512 hit barriers) ----
        unsigned short* lAh = (unsigned short*)(lsm);
        unsigned short* lAm = (unsigned short*)(lsm + 4096);
        unsigned short* lAl = (unsigned short*)(lsm + 8192);
        unsigned short* lWh = (unsigned short*)(lsm + 12288);
        unsigned short* lWm = (unsigned short*)(lsm + 16384);
        unsigned short* lWl = (unsigned short*)(lsm + 20480);
        const int i0 = blockIdx.x * 64;
        const int row = tid >> 2, c = tid & 3;
        const int wofs = row * 32 + ((c + (row >> 1)) & 3) * 8;
        f32x4 acc[4];
#pragma unroll
        for (int ns = 0; ns < 4; ++ns) acc[ns] = (f32x4){0.f, 0.f, 0.f, 0.f};
        const int ar = wave * 16 + ln;
        const int aofs = ar * 32 + ((quad + (ar >> 1)) & 3) * 8;
        int bofs[4];
#pragma unroll
        for (int ns = 0; ns < 4; ++ns) {
            const int br = ns * 16 + ln;
            bofs[ns] = br * 32 + ((quad + (br >> 1)) & 3) * 8;
        }
        for (int kt = 0; kt < 16; ++kt) {
            __syncthreads();
            if (tid < 256) {
                {
                    const float* src = xs + (size_t)(i0 + row) * DIM + kt * 32 + c * 8;
                    const float4 f0 = *(const float4*)src, f1 = *(const float4*)(src + 4);
                    float v[8] = {f0.x, f0.y, f0.z, f0.w, f1.x, f1.y, f1.z, f1.w};
                    u16x8 h8, m8, l8;
                    split3(v, h8, m8, l8);
                    *(u16x8*)(lAh + wofs) = h8;
                    *(u16x8*)(lAm + wofs) = m8;
                    *(u16x8*)(lAl + wofs) = l8;
                }
                {
                    const float* src = W1 + (size_t)row * DIM + kt * 32 + c * 8;
                    const float4 f0 = *(const float4*)src, f1 = *(const float4*)(src + 4);
                    float v[8] = {f0.x, f0.y, f0.z, f0.w, f1.x, f1.y, f1.z, f1.w};
                    u16x8 h8, m8, l8;
                    split3(v, h8, m8, l8);
                    *(u16x8*)(lWh + wofs) = h8;
                    *(u16x8*)(lWm + wofs) = m8;
                    *(u16x8*)(lWl + wofs) = l8;
                }
            }
            __syncthreads();
            if (tid < 256) {
                const bf16x8 ah = *(const bf16x8*)(lAh + aofs);
                const bf16x8 am = *(const bf16x8*)(lAm + aofs);
                const bf16x8 al = *(const bf16x8*)(lAl + aofs);
#pragma unroll
                for (int ns = 0; ns < 4; ++ns) {
                    const bf16x8 bh = *(const bf16x8*)(lWh + bofs[ns]);
                    const bf16x8 bm = *(const bf16x8*)(lWm + bofs[ns]);
                    const bf16x8 bl = *(const bf16x8*)(lWl + bofs[ns]);
                    acc[ns] = __builtin_amdgcn_mfma_f32_16x16x32_bf16(ah, bh, acc[ns], 0, 0, 0);
                    acc[ns] = __builtin_amdgcn_mfma_f32_16x16x32_bf16(ah, bm, acc[ns], 0, 0, 0);
                    acc[ns] = __builtin_amdgcn_mfma_f32_16x16x32_bf16(am, bh, acc[ns], 0, 0, 0);
                    acc[ns] = __builtin_amdgcn_mfma_f32_16x16x32_bf16(am, bm, acc[ns], 0, 0, 0);
                    acc[ns] = __builtin_amdgcn_mfma_f32_16x16x32_bf16(ah, bl, acc[ns], 0, 0, 0);
                    acc[ns] = __builtin_amdgcn_mfma_f32_16x16x32_bf16(al, bh, acc[ns], 0, 0, 0);
                }
            }
        }
        if (tid < 256) {
#pragma unroll
            for (int ns = 0; ns < 4; ++ns)
#pragma unroll
                for (int v = 0; v < 4; ++v)
                    P[(size_t)(i0 + wave * 16 + quad * 4 + v) * 64 + ns * 16 + ln] =
                        acc[ns][v];
        }
        return;
    }

    // ---- i8 nn body: direct-from-L2 fragments, no LDS, no barriers ----
    const int b = blockIdx.x - 128;
    const int xcd = b & 7, w = b >> 3;
    const int s = w >> 3, bil = w & 7;
    const int bi = xcd * 8 + bil;
    const int bj = (bi + s) & 63;
    const int i0 = bi * 128, j0 = bj * 128;
    const int m_off = (wave >> 1) * 32, n_off = (wave & 1) * 64;

    // fragment global bases: row (i0/j0 + off + ln), 16B chunk #quad of each
    // 64B kt-slice (quads of one row share a 64B cache line)
    const unsigned char* gA[2];
    const unsigned char* gB[4];
#pragma unroll
    for (int ms = 0; ms < 2; ++ms)
        gA[ms] = x8 + (size_t)(i0 + m_off + ms * 16 + ln) * DIM + quad * 16;
#pragma unroll
    for (int ns = 0; ns < 4; ++ns)
        gB[ns] = x8 + (size_t)(j0 + n_off + ns * 16 + ln) * DIM + quad * 16;

    i32x4 acc[2][4];
#pragma unroll
    for (int a = 0; a < 2; ++a)
#pragma unroll
        for (int c = 0; c < 4; ++c) acc[a][c] = (i32x4){0, 0, 0, 0};

#pragma unroll
    for (int kt = 0; kt < 8; ++kt) {
        i32x4 av[2], bv[4];
#pragma unroll
        for (int ms = 0; ms < 2; ++ms)
            av[ms] = *(const i32x4*)(gA[ms] + kt * 64);
#pragma unroll
        for (int ns = 0; ns < 4; ++ns)
            bv[ns] = *(const i32x4*)(gB[ns] + kt * 64);
#pragma unroll
        for (int ms = 0; ms < 2; ++ms)
#pragma unroll
            for (int ns = 0; ns < 4; ++ns)
                acc[ms][ns] = __builtin_amdgcn_mfma_i32_16x16x64_i8(
                    av[ms], bv[ns], acc[ms][ns], 0, 0, 0);
    }

    // ---- epilogue: full-d2 u32 keys; row-side LDS-transpose top-2 ----
    // (lsm untouched by the nn main loop -> rowbuf usable without a barrier;
    //  per-wave 4KB slice, same-wave write->read ordered by lgkmcnt)
    const bool diag = (s == 0);
    float sqj[4];
#pragma unroll
    for (int ns = 0; ns < 4; ++ns) sqj[ns] = sq[j0 + n_off + ns * 16 + ln];
    float sqi[2][4];
#pragma unroll
    for (int ms = 0; ms < 2; ++ms)
#pragma unroll
        for (int v = 0; v < 4; ++v)
            sqi[ms][v] = sq[i0 + m_off + ms * 16 + quad * 4 + v];

    unsigned long long* rowbuf = (unsigned long long*)(void*)lsm + (size_t)wave * 512;

    unsigned int c1[4], c2[4];
#pragma unroll
    for (int ns = 0; ns < 4; ++ns) { c1[ns] = 0xFFFFFFFFu; c2[ns] = 0xFFFFFFFFu; }

#pragma unroll
    for (int ms = 0; ms < 2; ++ms)
#pragma unroll
        for (int v = 0; v < 4; ++v) {
            const int gi = i0 + m_off + ms * 16 + quad * 4 + v;
            const float si = sqi[ms][v];
            unsigned int rp[4];
#pragma unroll
            for (int ns = 0; ns < 4; ++ns) {
                const int gj = j0 + n_off + ns * 16 + ln;
                float d2 = fmaf((float)acc[ms][ns][v], QD2, si + sqj[ns]);
                if (diag && gj == gi) d2 = __builtin_inff();
                const unsigned int ub = (__float_as_uint(d2) | 0x80000000u) & KMASK;
                rp[ns] = ub | (unsigned int)gj;
                const unsigned int cp = ub | (unsigned int)gi;
                c2[ns] = minu(c2[ns], maxu(c1[ns], cp));
                c1[ns] = minu(c1[ns], cp);
            }
            const unsigned int lo1 = minu(rp[0], rp[1]), hi1 = maxu(rp[0], rp[1]);
            const unsigned int lo2 = minu(rp[2], rp[3]), hi2 = maxu(rp[2], rp[3]);
            const unsigned int p1 = minu(lo1, lo2);
            const unsigned int p2 = minu(maxu(lo1, lo2), minu(hi1, hi2));
            const int rloc = ms * 16 + quad * 4 + v;
            rowbuf[rloc * 16 + ln] = (((unsigned long long)p1) << 32) | p2;
        }
    asm volatile("s_waitcnt lgkmcnt(0)" ::: "memory");  // same-wave write->read order

    {
        const int rr = lane & 31, hf = lane >> 5;
        unsigned int p1 = 0xFFFFFFFFu, p2 = 0xFFFFFFFFu;
#pragma unroll
        for (int k = 0; k < 8; ++k) {
            const int pos = hf * 8 + (k ^ (rr & 7));
            const unsigned long long pw = rowbuf[rr * 16 + pos];
            const unsigned int a1 = (unsigned int)(pw >> 32), a2 = (unsigned int)pw;
            p2 = minu(minu(p2, a2), maxu(p1, a1));
            p1 = minu(p1, a1);
        }
        const unsigned long long mine = (((unsigned long long)p1) << 32) | p2;
        const unsigned long long oth = __shfl_xor(mine, 32);
        {
            const unsigned int a1 = (unsigned int)(oth >> 32), a2 = (unsigned int)oth;
            p2 = minu(minu(p2, a2), maxu(p1, a1));
            p1 = minu(p1, a1);
        }
        if (lane < 32) {
            const int gi = i0 + m_off + rr;
            const size_t base = ((size_t)gi * NSLOT + (s * 2 + (wave & 1))) * 2;
            rowtab[base] = p1;
            rowtab[base + 1] = p2;
        }
    }

    if (s > 0) {
#pragma unroll
        for (int ns = 0; ns < 4; ++ns) {
            unsigned int q1 = c1[ns], q2 = c2[ns];
#pragma unroll
            for (int d = 16; d <= 32; d <<= 1) {
                const unsigned long long pr = (((unsigned long long)q1) << 32) | q2;
                const unsigned long long o = __shfl_xor(pr, d);
                const unsigned int a1 = (unsigned int)(o >> 32), a2 = (unsigned int)o;
                q2 = minu(minu(q2, a2), maxu(q1, a1));
                q1 = minu(q1, a1);
            }
            if (lane < 16) {
                const int gj = j0 + n_off + ns * 16 + ln;
                const size_t base =
                    ((size_t)gj * NSLOT + (66 + (s - 1) * 4 + (wave >> 1))) * 2;
                rowtab[base] = q1;
                rowtab[base + 1] = q2;
            }
        }
    }
}

// ---------------------------------------------------------------- k_refine_mid
// FUSED refine + mid (r7/r9/r10-proven: padded weight LDS, readlane
// broadcasts, i8 margin 5, dual-accumulator MLP chains).
__global__ __launch_bounds__(512, 6) void k_refine_mid(
    const unsigned int* __restrict__ rowtab, const float* __restrict__ xs,
    const float* __restrict__ sq, const float* __restrict__ P,
    const float* __restrict__ b1, const float* __restrict__ W2,
    const float* __restrict__ b2, const float* __restrict__ W3,
    const float* __restrict__ b3, const float* __restrict__ D1,
    const float* __restrict__ d1, const float* __restrict__ D2,
    const float* __restrict__ d2, float* __restrict__ out_zs,
    float* __restrict__ G2) {
    __shared__ float W2T[64 * 33], W3T[32 * 33], D1T[32 * 33], D2T[32 * 65];
    __shared__ float b2f[32], b3f[32], d1f[32], d2f[64];
    __shared__ unsigned int clist[4][64];
    __shared__ int ccnt[4];
    __shared__ unsigned int rowbest[4];
    __shared__ unsigned int nnr_s[4];
    __shared__ float pbuf[4][64 * 8];  // [row-in-block][cand*8 + group8]
    const int tid = threadIdx.x;
    const int wave = tid >> 6, lane = tid & 63;
    const int r = wave & 3, half = wave >> 2;  // 2 waves (half 0/1) per row
    const int row = blockIdx.x * 4 + r;
    // stage MLP weights (transposed, PADDED) while refine's table scan runs
    for (int t = tid; t < 2048; t += 512) { int o = t >> 6, k = t & 63; W2T[k * 33 + o] = W2[t]; }
    for (int t = tid; t < 1024; t += 512) { int o = t >> 5, k = t & 31; W3T[k * 33 + o] = W3[t]; }
    for (int t = tid; t < 1024; t += 512) { int o = t >> 5, k = t & 31; D1T[k * 33 + o] = D1[t]; }
    for (int t = tid; t < 2048; t += 512) { int o = t >> 5, k = t & 31; D2T[k * 65 + o] = D2[t]; }
    if (tid < 32) b2f[tid] = b2[tid];
    else if (tid < 64) b3f[tid - 32] = b3[tid - 32];
    else if (tid < 96) d1f[tid - 64] = d1[tid - 64];
    else if (tid < 160) d2f[tid - 96] = d2[tid - 96];
    if (tid < 4) { ccnt[tid] = 0; rowbest[tid] = 0xFFFFFFFFu; }
    __syncthreads();

    // ---- refine: split table scan (each wave-half scans stride-128) ----
    unsigned int vals[4];
    int nv = 0;
    unsigned int best = 0xFFFFFFFFu;
    for (int i = half * 64 + lane; i < NSLOT * 2; i += 128) {
        const unsigned int v = rowtab[(size_t)row * NSLOT * 2 + i];
        vals[nv++] = v;
        best = minu(best, v);
    }
#pragma unroll
    for (int d = 1; d < 64; d <<= 1) best = minu(best, __shfl_xor(best, d));
    if (lane == 0) atomicMin(&rowbest[r], best);
    __syncthreads();
    best = rowbest[r];

    const float dmin = unfkey(best & KMASK);
    const unsigned int tkey = fkey(dmin + 5.0f);
    for (int k = 0; k < nv; ++k)
        if ((vals[k] & KMASK) < tkey) {
            const int p = atomicAdd(&ccnt[r], 1);
            if (p < 64) clist[r][p] = vals[k] & 8191u;
        }
    __syncthreads();
    int cnt = ccnt[r];
    cnt = cnt > 64 ? 64 : cnt;

    // ---- exact distances: 2-wave parity split + depth-1 prefetch ----
    const float4* xi = (const float4*)(xs + (size_t)row * DIM);
    const float4 x0 = xi[2 * lane], x1 = xi[2 * lane + 1];
    const float sqi = sq[row];
    const int g8 = lane >> 3;
    float4 cy0 = {0.f, 0.f, 0.f, 0.f}, cy1 = {0.f, 0.f, 0.f, 0.f};
    if (half < cnt) {
        const float4* xj = (const float4*)(xs + (size_t)clist[r][half] * DIM);
        cy0 = xj[2 * lane];
        cy1 = xj[2 * lane + 1];
    }
    for (int c = half; c < cnt; c += 2) {
        float4 ny0 = {0.f, 0.f, 0.f, 0.f}, ny1 = {0.f, 0.f, 0.f, 0.f};
        const int cn = c + 2;
        if (cn < cnt) {  // issue next-candidate load before current compute
            const float4* xj = (const float4*)(xs + (size_t)clist[r][cn] * DIM);
            ny0 = xj[2 * lane];
            ny1 = xj[2 * lane + 1];
        }
        float dot = 0.f;
        dot = fmaf(x0.x, cy0.x, dot); dot = fmaf(x0.y, cy0.y, dot);
        dot = fmaf(x0.z, cy0.z, dot); dot = fmaf(x0.w, cy0.w, dot);
        dot = fmaf(x1.x, cy1.x, dot); dot = fmaf(x1.y, cy1.y, dot);
        dot = fmaf(x1.z, cy1.z, dot); dot = fmaf(x1.w, cy1.w, dot);
        dot += __shfl_xor(dot, 1);
        dot += __shfl_xor(dot, 2);
        dot += __shfl_xor(dot, 4);
        if ((lane & 7) == 0) pbuf[r][c * 8 + g8] = dot;
        cy0 = ny0;
        cy1 = ny1;
    }
    __syncthreads();  // cross-wave pbuf visibility

    // ---- batch gather + single min-reduce (half-0 wave only) ----
    if (half == 0) {
        unsigned long long key = ~0ull;
        if (lane < cnt) {
            const unsigned int j = clist[r][lane];
            float dot = 0.f;
#pragma unroll
            for (int k = 0; k < 8; ++k)
                dot += pbuf[r][lane * 8 + ((k + lane + (lane >> 3)) & 7)];
            const float d2v = sqi + sq[j] - 2.f * dot;
            key = (((unsigned long long)fkey(d2v)) << 32) | j;
        }
#pragma unroll
        for (int d = 1; d < 64; d <<= 1) key = min64(key, __shfl_xor(key, d));
        if (lane == 0) nnr_s[r] = (unsigned int)(key & 0xFFFFFFFFull) & 8191u;
    }
    __syncthreads();
    if (half == 1) return;  // no barriers past this point
    const unsigned int nnr = nnr_s[r];

    // ---- mid (readlane broadcasts; dual-accumulator ILP) ----
    const int o32 = lane & 31;
    const float b1v = b1[lane];
    const float pr = P[(size_t)row * 64 + lane];
    const float p0 = P[(size_t)nnr * 64 + lane];
    const float a1 = p0 + b1v;
    const float u1 = pr - p0;
    const float h1 = fmaxf(a1, 0.f);
    const float th1 = (a1 > 0.f) ? u1 : 0.f;
    float a2a = b2f[o32], a2b = 0.f, u2a = 0.f, u2b = 0.f;
#pragma unroll
    for (int k = 0; k < 64; k += 2) {
        const float ha = bcastf(h1, k), hb = bcastf(h1, k + 1);
        const float ta = bcastf(th1, k), tb = bcastf(th1, k + 1);
        const float wa = W2T[k * 33 + o32], wb = W2T[(k + 1) * 33 + o32];
        a2a = fmaf(ha, wa, a2a);
        a2b = fmaf(hb, wb, a2b);
        u2a = fmaf(ta, wa, u2a);
        u2b = fmaf(tb, wb, u2b);
    }
    const float a2 = a2a + a2b;
    const float u2 = u2a + u2b;
    const float sv = fmaxf(a2, 0.f) + ((a2 > 0.f) ? u2 : 0.f);
    float za = b3f[o32], zb = 0.f;
#pragma unroll
    for (int k = 0; k < 32; k += 2) {
        za = fmaf(bcastf(sv, k), W3T[k * 33 + o32], za);
        zb = fmaf(bcastf(sv, k + 1), W3T[(k + 1) * 33 + o32], zb);
    }
    const float z = za + zb;
    if (lane < 32) out_zs[(size_t)row * 32 + lane] = z;
    float g1a = d1f[o32], g1b = 0.f;
#pragma unroll
    for (int k = 0; k < 32; k += 2) {
        g1a = fmaf(bcastf(z, k), D1T[k * 33 + o32], g1a);
        g1b = fmaf(bcastf(z, k + 1), D1T[(k + 1) * 33 + o32], g1b);
    }
    const float g1 = fmaxf(g1a + g1b, 0.f);
    float g2a = d2f[lane], g2b = 0.f;
#pragma unroll
    for (int k = 0; k < 32; k += 2) {
        g2a = fmaf(bcastf(g1, k), D2T[k * 65 + lane], g2a);
        g2b = fmaf(bcastf(g1, k + 1), D2T[(k + 1) * 65 + lane], g2b);
    }
    const float g2 = fmaxf(g2a + g2b, 0.f);
    G2[(size_t)row * 64 + lane] = g2;
}

// ---------------------------------------------------------------- k_dec
// 512 threads / 8 waves: per-wave 64x32 tile. Same math, same grid.
__global__ __launch_bounds__(512) void k_dec(const float* __restrict__ G2,
                                             const float* __restrict__ D3,
                                             const float* __restrict__ d3,
                                             float* __restrict__ xhat) {
    __shared__ __align__(16) unsigned short lGh[128 * 64], lGl[128 * 64];
    __shared__ __align__(16) unsigned short lDh[128 * 64], lDl[128 * 64];
    const int tid = threadIdx.x, wave = tid >> 6, lane = tid & 63, quad = lane >> 4,
              ln = lane & 15;
    const int i0 = blockIdx.x * 128, nbase = blockIdx.y * 128;
    const int m_off = (wave & 1) * 64, n_off = (wave >> 1) * 32;
#pragma unroll
    for (int r = 0; r < 2; ++r) {
        const int g = r * 512 + tid;
        const int row = g >> 3, cIdx = g & 7, half = cIdx >> 2, cc = cIdx & 3;
        const int wofs = row * 64 + half * 32 + ((cc + (row >> 1)) & 3) * 8;
        {
            const float* src = G2 + (size_t)(i0 + row) * 64 + cIdx * 8;
            const float4 f0 = *(const float4*)src, f1 = *(const float4*)(src + 4);
            float v[8] = {f0.x, f0.y, f0.z, f0.w, f1.x, f1.y, f1.z, f1.w};
            u16x8 h8, l8;
            split2(v, h8, l8);
            *(u16x8*)(lGh + wofs) = h8;
            *(u16x8*)(lGl + wofs) = l8;
        }
        {
            const float* src = D3 + (size_t)(nbase + row) * 64 + cIdx * 8;
            const float4 f0 = *(const float4*)src, f1 = *(const float4*)(src + 4);
            float v[8] = {f0.x, f0.y, f0.z, f0.w, f1.x, f1.y, f1.z, f1.w};
            u16x8 h8, l8;
            split2(v, h8, l8);
            *(u16x8*)(lDh + wofs) = h8;
            *(u16x8*)(lDl + wofs) = l8;
        }
    }
    __syncthreads();
    f32x4 acc[4][2];
#pragma unroll
    for (int a = 0; a < 4; ++a)
#pragma unroll
        for (int c = 0; c < 2; ++c) acc[a][c] = (f32x4){0.f, 0.f, 0.f, 0.f};
#pragma unroll
    for (int kk = 0; kk < 2; ++kk) {
        bf16x8 ah[4], al[4], bh[2], bl[2];
#pragma unroll
        for (int ms = 0; ms < 4; ++ms) {
            const int ar = m_off + ms * 16 + ln;
            const int aofs = ar * 64 + kk * 32 + ((quad + (ar >> 1)) & 3) * 8;
            ah[ms] = *(const bf16x8*)(lGh + aofs);
            al[ms] = *(const bf16x8*)(lGl + aofs);
        }
#pragma unroll
        for (int ns = 0; ns < 2; ++ns) {
            const int br = n_off + ns * 16 + ln;
            const int bofs = br * 64 + kk * 32 + ((quad + (br >> 1)) & 3) * 8;
            bh[ns] = *(const bf16x8*)(lDh + bofs);
            bl[ns] = *(const bf16x8*)(lDl + bofs);
        }
#pragma unroll
        for (int ms = 0; ms < 4; ++ms)
#pragma unroll
            for (int ns = 0; ns < 2; ++ns) {
                acc[ms][ns] = __builtin_amdgcn_mfma_f32_16x16x32_bf16(
                    ah[ms], bh[ns], acc[ms][ns], 0, 0, 0);
                acc[ms][ns] = __builtin_amdgcn_mfma_f32_16x16x32_bf16(
                    ah[ms], bl[ns], acc[ms][ns], 0, 0, 0);
                acc[ms][ns] = __builtin_amdgcn_mfma_f32_16x16x32_bf16(
                    al[ms], bh[ns], acc[ms][ns], 0, 0, 0);
            }
    }
    float d3f[2];
#pragma unroll
    for (int ns = 0; ns < 2; ++ns) d3f[ns] = d3[nbase + n_off + ns * 16 + ln];
#pragma unroll
    for (int ms = 0; ms < 4; ++ms)
#pragma unroll
        for (int ns = 0; ns < 2; ++ns)
#pragma unroll
            for (int v = 0; v < 4; ++v) {
                const int m = m_off + ms * 16 + quad * 4 + v;
                const int n = n_off + ns * 16 + ln;
                xhat[(size_t)(i0 + m) * DIM + nbase + n] = acc[ms][ns][v] + d3f[ns];
            }
}

extern "C" void kernel_launch(void* const* d_in, const int* in_sizes, int n_in,
                              void* d_out, int out_size, void* d_ws, size_t ws_size,
                              hipStream_t stream) {
    const float* xs = (const float*)d_in[0];
    const float* W1 = (const float*)d_in[1];
    const float* b1 = (const float*)d_in[2];
    const float* W2 = (const float*)d_in[3];
    const float* b2 = (const float*)d_in[4];
    const float* W3 = (const float*)d_in[5];
    const float* b3 = (const float*)d_in[6];
    const float* D1 = (const float*)d_in[7];
    const float* d1 = (const float*)d_in[8];
    const float* D2 = (const float*)d_in[9];
    const float* d2 = (const float*)d_in[10];
    const float* D3 = (const float*)d_in[11];
    const float* d3 = (const float*)d_in[12];

    // ws: sq(32K) | gap | xs_i8 (4 MB) | P | G2   (proven layout)
    char* ws = (char*)d_ws;
    float* sq = (float*)(ws);                                     // 32 KB
    unsigned char* xs_i8 = (unsigned char*)(ws + 131072);         // 4 MB
    float* P = (float*)(ws + 8519680);                            // 2 MB
    float* G2 = (float*)(ws + 10616832);                          // 2 MB

    float* xhat = (float*)d_out;
    float* zs = (float*)d_out + (size_t)NROWS * DIM;
    // rowtab scratch (u32, 8192*194*2*4 = 12.7 MB) lives in d_out's dead space
    unsigned int* rowtab = (unsigned int*)d_out;

    hipLaunchKernelGGL(k_prep, dim3(2048), dim3(256), 0, stream, xs, xs_i8, sq);
    hipLaunchKernelGGL(k_nn, dim3(2240), dim3(512), 0, stream, xs_i8, sq, rowtab, xs,
                       W1, P);
    hipLaunchKernelGGL(k_refine_mid, dim3(2048), dim3(512), 0, stream, rowtab, xs, sq,
                       P, b1, W2, b2, W3, b3, D1, d1, D2, d2, zs, G2);
    hipLaunchKernelGGL(k_dec, dim3(64, 4), dim3(512), 0, stream, G2, D3, d3, xhat);
}

// Round 12
// 162.497 us; speedup vs baseline: 1.3781x; 1.3781x over previous
//
#include <hip/hip_runtime.h>
#include <hip/hip_bf16.h>

#define NROWS 8192
#define DIM 512
#define NSLOT 194  // per-row top-2 slots: 66 row-side + 128 col-side (32 s x 4 row-groups)
#define KMASK 0xFFFFE000u  // top-19 key bits; low 13 = index
#define QSCALE 21.0f       // i8 quantization scale: clamp +-6.05 (> global max ~5.2)
#define QD2 (-2.0f / (QSCALE * QSCALE))

typedef __attribute__((ext_vector_type(8))) short bf16x8;
typedef __attribute__((ext_vector_type(4))) float f32x4;
typedef __attribute__((ext_vector_type(4))) int i32x4;
typedef __attribute__((ext_vector_type(8))) unsigned short u16x8;

__device__ __forceinline__ float bf2f(unsigned short u) {
    return __uint_as_float(((unsigned int)u) << 16);
}
__device__ __forceinline__ unsigned short f2bf(float f) {
    unsigned int b = __float_as_uint(f);
    return (unsigned short)((b + 0x7FFFu + ((b >> 16) & 1u)) >> 16);
}
// fp32 -> signed i8, RNE, scale QSCALE (no clipping for N(0,1): 127/21=6.05 > max ~5.2)
__device__ __forceinline__ unsigned char f2i8(float x) {
    float s = x * QSCALE;
    s = fminf(fmaxf(s, -127.f), 127.f);
    const int q = __float2int_rn(s);
    return (unsigned char)(q & 0xFF);
}
// monotone float->uint key
__device__ __forceinline__ unsigned int fkey(float f) {
    unsigned int b = __float_as_uint(f);
    return (b & 0x80000000u) ? ~b : (b | 0x80000000u);
}
__device__ __forceinline__ float unfkey(unsigned int u) {
    unsigned int b = (u & 0x80000000u) ? (u ^ 0x80000000u) : ~u;
    return __uint_as_float(b);
}
__device__ __forceinline__ unsigned int minu(unsigned int a, unsigned int b) {
    return a < b ? a : b;
}
__device__ __forceinline__ unsigned int maxu(unsigned int a, unsigned int b) {
    return a > b ? a : b;
}
__device__ __forceinline__ unsigned long long min64(unsigned long long a,
                                                    unsigned long long b) {
    return a < b ? a : b;
}
// VALU-pipe lane broadcast (v_readlane, compile-time k) -- r7-proven DS-pipe fix.
__device__ __forceinline__ float bcastf(float v, int k) {
    return __uint_as_float((unsigned int)__builtin_amdgcn_readlane(__float_as_uint(v), k));
}

// helper: 3-way bf16 split
__device__ __forceinline__ void split3(const float* v, u16x8& h8, u16x8& m8, u16x8& l8) {
#pragma unroll
    for (int j = 0; j < 8; ++j) {
        const float x = v[j];
        const unsigned short h = f2bf(x);
        const float r1 = x - bf2f(h);
        const unsigned short m = f2bf(r1);
        const float r2 = r1 - bf2f(m);
        h8[j] = h; m8[j] = m; l8[j] = f2bf(r2);
    }
}
// helper: 2-way split
__device__ __forceinline__ void split2(const float* v, u16x8& h8, u16x8& l8) {
#pragma unroll
    for (int j = 0; j < 8; ++j) {
        const float x = v[j];
        const unsigned short h = f2bf(x);
        h8[j] = h; l8[j] = f2bf(x - bf2f(h));
    }
}

// ---------------------------------------------------------------- k_prep
// Prep ONLY (i8 plane + sq): 2048 blocks, HBM-bound (~20 MB traffic).
__global__ __launch_bounds__(256) void k_prep(const float* __restrict__ xs,
                                              unsigned char* __restrict__ x8,
                                              float* __restrict__ sq) {
    const int tid = threadIdx.x;
    const int wave = tid >> 6, lane = tid & 63;
    const int row = blockIdx.x * 4 + wave;
    const float4* xr = (const float4*)(xs + (size_t)row * DIM);
    const float4 a = xr[2 * lane], b = xr[2 * lane + 1];
    float v[8] = {a.x, a.y, a.z, a.w, b.x, b.y, b.z, b.w};
    unsigned long long pk8 = 0ull;
    float s = 0.f;
#pragma unroll
    for (int i = 0; i < 8; ++i) {
        pk8 |= ((unsigned long long)f2i8(v[i])) << (8 * i);
        s = fmaf(v[i], v[i], s);
    }
    *(unsigned long long*)(x8 + (size_t)row * DIM + lane * 8) = pk8;
#pragma unroll
    for (int d = 32; d; d >>= 1) s += __shfl_xor(s, d);
    if (lane == 0) sq[row] = s;
}

// ---------------------------------------------------------------- k_nn
// REVERTED to the r10-proven LDS+DMA structure (r11's direct-from-L2 variant
// regressed 2.5x: one fragment load spans 16 rows = 16 cache lines -> TA-pipe
// serialization; the LDS round-trip IS the layout transpose, not overhead).
// Single change vs r10: __launch_bounds__(512, 8) -- VGPR 44 <= 64 and
// 32KB LDS x 4 <= 160KB both allow 4 blocks/CU (32 waves, was 2 blocks/16),
// doubling the waves available to hide per-kt barrier drains + DMA latency
// (the r1->r2 occupancy mechanism, 2x win there).
// Blocks 0..127: P = xs @ W1^T (tid<256 guard). Blocks 128..2239: i8 nn.
__global__ __launch_bounds__(512, 8) void k_nn(const unsigned char* __restrict__ x8,
                                               const float* __restrict__ sq,
                                               unsigned int* __restrict__ rowtab,
                                               const float* __restrict__ xs,
                                               const float* __restrict__ W1,
                                               float* __restrict__ P) {
    __shared__ __align__(16) unsigned char lsm[32768];
    const int tid = threadIdx.x;
    const int wave = tid >> 6, lane = tid & 63, quad = lane >> 4, ln = lane & 15;

    if (blockIdx.x < 128) {
        // ---- P-GEMM tile (256 active threads; all 512 hit barriers) ----
        unsigned short* lAh = (unsigned short*)(lsm);
        unsigned short* lAm = (unsigned short*)(lsm + 4096);
        unsigned short* lAl = (unsigned short*)(lsm + 8192);
        unsigned short* lWh = (unsigned short*)(lsm + 12288);
        unsigned short* lWm = (unsigned short*)(lsm + 16384);
        unsigned short* lWl = (unsigned short*)(lsm + 20480);
        const int i0 = blockIdx.x * 64;
        const int row = tid >> 2, c = tid & 3;
        const int wofs = row * 32 + ((c + (row >> 1)) & 3) * 8;
        f32x4 acc[4];
#pragma unroll
        for (int ns = 0; ns < 4; ++ns) acc[ns] = (f32x4){0.f, 0.f, 0.f, 0.f};
        const int ar = wave * 16 + ln;
        const int aofs = ar * 32 + ((quad + (ar >> 1)) & 3) * 8;
        int bofs[4];
#pragma unroll
        for (int ns = 0; ns < 4; ++ns) {
            const int br = ns * 16 + ln;
            bofs[ns] = br * 32 + ((quad + (br >> 1)) & 3) * 8;
        }
        for (int kt = 0; kt < 16; ++kt) {
            __syncthreads();
            if (tid < 256) {
                {
                    const float* src = xs + (size_t)(i0 + row) * DIM + kt * 32 + c * 8;
                    const float4 f0 = *(const float4*)src, f1 = *(const float4*)(src + 4);
                    float v[8] = {f0.x, f0.y, f0.z, f0.w, f1.x, f1.y, f1.z, f1.w};
                    u16x8 h8, m8, l8;
                    split3(v, h8, m8, l8);
                    *(u16x8*)(lAh + wofs) = h8;
                    *(u16x8*)(lAm + wofs) = m8;
                    *(u16x8*)(lAl + wofs) = l8;
                }
                {
                    const float* src = W1 + (size_t)row * DIM + kt * 32 + c * 8;
                    const float4 f0 = *(const float4*)src, f1 = *(const float4*)(src + 4);
                    float v[8] = {f0.x, f0.y, f0.z, f0.w, f1.x, f1.y, f1.z, f1.w};
                    u16x8 h8, m8, l8;
                    split3(v, h8, m8, l8);
                    *(u16x8*)(lWh + wofs) = h8;
                    *(u16x8*)(lWm + wofs) = m8;
                    *(u16x8*)(lWl + wofs) = l8;
                }
            }
            __syncthreads();
            if (tid < 256) {
                const bf16x8 ah = *(const bf16x8*)(lAh + aofs);
                const bf16x8 am = *(const bf16x8*)(lAm + aofs);
                const bf16x8 al = *(const bf16x8*)(lAl + aofs);
#pragma unroll
                for (int ns = 0; ns < 4; ++ns) {
                    const bf16x8 bh = *(const bf16x8*)(lWh + bofs[ns]);
                    const bf16x8 bm = *(const bf16x8*)(lWm + bofs[ns]);
                    const bf16x8 bl = *(const bf16x8*)(lWl + bofs[ns]);
                    acc[ns] = __builtin_amdgcn_mfma_f32_16x16x32_bf16(ah, bh, acc[ns], 0, 0, 0);
                    acc[ns] = __builtin_amdgcn_mfma_f32_16x16x32_bf16(ah, bm, acc[ns], 0, 0, 0);
                    acc[ns] = __builtin_amdgcn_mfma_f32_16x16x32_bf16(am, bh, acc[ns], 0, 0, 0);
                    acc[ns] = __builtin_amdgcn_mfma_f32_16x16x32_bf16(am, bm, acc[ns], 0, 0, 0);
                    acc[ns] = __builtin_amdgcn_mfma_f32_16x16x32_bf16(ah, bl, acc[ns], 0, 0, 0);
                    acc[ns] = __builtin_amdgcn_mfma_f32_16x16x32_bf16(al, bh, acc[ns], 0, 0, 0);
                }
            }
        }
        if (tid < 256) {
#pragma unroll
            for (int ns = 0; ns < 4; ++ns)
#pragma unroll
                for (int v = 0; v < 4; ++v)
                    P[(size_t)(i0 + wave * 16 + quad * 4 + v) * 64 + ns * 16 + ln] =
                        acc[ns][v];
        }
        return;
    }

    // ---- i8 nn body (r10-proven: LDS double-buffer + DMA + pair swizzle) ----
    unsigned char* lA = lsm;            // A tiles: 2 x 8192
    unsigned char* lB = lsm + 16384;    // B tiles: 2 x 8192
    const int b = blockIdx.x - 128;
    const int xcd = b & 7, w = b >> 3;
    const int s = w >> 3, bil = w & 7;
    const int bi = xcd * 8 + bil;
    const int bj = (bi + s) & 63;
    const int i0 = bi * 128, j0 = bj * 128;
    const int m_off = (wave >> 1) * 32, n_off = (wave & 1) * 64;

    const int rl = lane >> 2;
    const int sp = ((lane & 3) - ((rl >> 1) & 3)) & 3;
    const unsigned char* gpA = x8 + (size_t)(i0 + wave * 16 + rl) * DIM + sp * 16;
    const unsigned char* gpB = x8 + (size_t)(j0 + wave * 16 + rl) * DIM + sp * 16;
    unsigned char* dstA = lA + wave * 1024;
    unsigned char* dstB = lB + wave * 1024;

    // K=64 fragment: one b128 per (ms)/(ns) -- pair quad at swizzled pos
    int aoff[2], boff[4];
#pragma unroll
    for (int ms = 0; ms < 2; ++ms) {
        const int r = m_off + ms * 16 + ln;
        aoff[ms] = r * 64 + ((quad + ((r >> 1) & 3)) & 3) * 16;
    }
#pragma unroll
    for (int ns = 0; ns < 4; ++ns) {
        const int r = n_off + ns * 16 + ln;
        boff[ns] = r * 64 + ((quad + ((r >> 1) & 3)) & 3) * 16;
    }

    i32x4 acc[2][4];
#pragma unroll
    for (int a = 0; a < 2; ++a)
#pragma unroll
        for (int c = 0; c < 4; ++c) acc[a][c] = (i32x4){0, 0, 0, 0};

    __builtin_amdgcn_global_load_lds(
        (const __attribute__((address_space(1))) void*)gpA,
        (__attribute__((address_space(3))) void*)dstA, 16, 0, 0);
    __builtin_amdgcn_global_load_lds(
        (const __attribute__((address_space(1))) void*)gpB,
        (__attribute__((address_space(3))) void*)dstB, 16, 0, 0);

#pragma unroll
    for (int kt = 0; kt < 8; ++kt) {
        __syncthreads();  // drains DMA filling buf[kt&1]; prior reads done
        if (kt < 7) {
            const int nxt = ((kt + 1) & 1) * 8192;
            __builtin_amdgcn_global_load_lds(
                (const __attribute__((address_space(1))) void*)(gpA + (kt + 1) * 64),
                (__attribute__((address_space(3))) void*)(dstA + nxt), 16, 0, 0);
            __builtin_amdgcn_global_load_lds(
                (const __attribute__((address_space(1))) void*)(gpB + (kt + 1) * 64),
                (__attribute__((address_space(3))) void*)(dstB + nxt), 16, 0, 0);
        }
        const int cur = (kt & 1) * 8192;
        i32x4 av[2], bv[4];
#pragma unroll
        for (int ms = 0; ms < 2; ++ms)
            av[ms] = *(const i32x4*)(lA + cur + aoff[ms]);
#pragma unroll
        for (int ns = 0; ns < 4; ++ns)
            bv[ns] = *(const i32x4*)(lB + cur + boff[ns]);
#pragma unroll
        for (int ms = 0; ms < 2; ++ms)
#pragma unroll
            for (int ns = 0; ns < 4; ++ns)
                acc[ms][ns] = __builtin_amdgcn_mfma_i32_16x16x64_i8(
                    av[ms], bv[ns], acc[ms][ns], 0, 0, 0);
    }
    __syncthreads();  // all waves done reading lA/lB -> safe to reuse as rowbuf

    // ---- epilogue: full-d2 u32 keys; row-side LDS-transpose top-2 ----
    const bool diag = (s == 0);
    float sqj[4];
#pragma unroll
    for (int ns = 0; ns < 4; ++ns) sqj[ns] = sq[j0 + n_off + ns * 16 + ln];
    float sqi[2][4];
#pragma unroll
    for (int ms = 0; ms < 2; ++ms)
#pragma unroll
        for (int v = 0; v < 4; ++v)
            sqi[ms][v] = sq[i0 + m_off + ms * 16 + quad * 4 + v];

    unsigned long long* rowbuf = (unsigned long long*)(void*)lsm + (size_t)wave * 512;

    unsigned int c1[4], c2[4];
#pragma unroll
    for (int ns = 0; ns < 4; ++ns) { c1[ns] = 0xFFFFFFFFu; c2[ns] = 0xFFFFFFFFu; }

#pragma unroll
    for (int ms = 0; ms < 2; ++ms)
#pragma unroll
        for (int v = 0; v < 4; ++v) {
            const int gi = i0 + m_off + ms * 16 + quad * 4 + v;
            const float si = sqi[ms][v];
            unsigned int rp[4];
#pragma unroll
            for (int ns = 0; ns < 4; ++ns) {
                const int gj = j0 + n_off + ns * 16 + ln;
                float d2 = fmaf((float)acc[ms][ns][v], QD2, si + sqj[ns]);
                if (diag && gj == gi) d2 = __builtin_inff();
                const unsigned int ub = (__float_as_uint(d2) | 0x80000000u) & KMASK;
                rp[ns] = ub | (unsigned int)gj;
                const unsigned int cp = ub | (unsigned int)gi;
                c2[ns] = minu(c2[ns], maxu(c1[ns], cp));
                c1[ns] = minu(c1[ns], cp);
            }
            const unsigned int lo1 = minu(rp[0], rp[1]), hi1 = maxu(rp[0], rp[1]);
            const unsigned int lo2 = minu(rp[2], rp[3]), hi2 = maxu(rp[2], rp[3]);
            const unsigned int p1 = minu(lo1, lo2);
            const unsigned int p2 = minu(maxu(lo1, lo2), minu(hi1, hi2));
            const int rloc = ms * 16 + quad * 4 + v;
            rowbuf[rloc * 16 + ln] = (((unsigned long long)p1) << 32) | p2;
        }
    asm volatile("s_waitcnt lgkmcnt(0)" ::: "memory");  // same-wave write->read order

    {
        const int rr = lane & 31, hf = lane >> 5;
        unsigned int p1 = 0xFFFFFFFFu, p2 = 0xFFFFFFFFu;
#pragma unroll
        for (int k = 0; k < 8; ++k) {
            const int pos = hf * 8 + (k ^ (rr & 7));
            const unsigned long long pw = rowbuf[rr * 16 + pos];
            const unsigned int a1 = (unsigned int)(pw >> 32), a2 = (unsigned int)pw;
            p2 = minu(minu(p2, a2), maxu(p1, a1));
            p1 = minu(p1, a1);
        }
        const unsigned long long mine = (((unsigned long long)p1) << 32) | p2;
        const unsigned long long oth = __shfl_xor(mine, 32);
        {
            const unsigned int a1 = (unsigned int)(oth >> 32), a2 = (unsigned int)oth;
            p2 = minu(minu(p2, a2), maxu(p1, a1));
            p1 = minu(p1, a1);
        }
        if (lane < 32) {
            const int gi = i0 + m_off + rr;
            const size_t base = ((size_t)gi * NSLOT + (s * 2 + (wave & 1))) * 2;
            rowtab[base] = p1;
            rowtab[base + 1] = p2;
        }
    }

    if (s > 0) {
#pragma unroll
        for (int ns = 0; ns < 4; ++ns) {
            unsigned int q1 = c1[ns], q2 = c2[ns];
#pragma unroll
            for (int d = 16; d <= 32; d <<= 1) {
                const unsigned long long pr = (((unsigned long long)q1) << 32) | q2;
                const unsigned long long o = __shfl_xor(pr, d);
                const unsigned int a1 = (unsigned int)(o >> 32), a2 = (unsigned int)o;
                q2 = minu(minu(q2, a2), maxu(q1, a1));
                q1 = minu(q1, a1);
            }
            if (lane < 16) {
                const int gj = j0 + n_off + ns * 16 + ln;
                const size_t base =
                    ((size_t)gj * NSLOT + (66 + (s - 1) * 4 + (wave >> 1))) * 2;
                rowtab[base] = q1;
                rowtab[base + 1] = q2;
            }
        }
    }
}

// ---------------------------------------------------------------- k_refine_mid
// FUSED refine + mid (r7/r9/r10-proven: padded weight LDS, readlane
// broadcasts, i8 margin 5, dual-accumulator MLP chains).
__global__ __launch_bounds__(512, 6) void k_refine_mid(
    const unsigned int* __restrict__ rowtab, const float* __restrict__ xs,
    const float* __restrict__ sq, const float* __restrict__ P,
    const float* __restrict__ b1, const float* __restrict__ W2,
    const float* __restrict__ b2, const float* __restrict__ W3,
    const float* __restrict__ b3, const float* __restrict__ D1,
    const float* __restrict__ d1, const float* __restrict__ D2,
    const float* __restrict__ d2, float* __restrict__ out_zs,
    float* __restrict__ G2) {
    __shared__ float W2T[64 * 33], W3T[32 * 33], D1T[32 * 33], D2T[32 * 65];
    __shared__ float b2f[32], b3f[32], d1f[32], d2f[64];
    __shared__ unsigned int clist[4][64];
    __shared__ int ccnt[4];
    __shared__ unsigned int rowbest[4];
    __shared__ unsigned int nnr_s[4];
    __shared__ float pbuf[4][64 * 8];  // [row-in-block][cand*8 + group8]
    const int tid = threadIdx.x;
    const int wave = tid >> 6, lane = tid & 63;
    const int r = wave & 3, half = wave >> 2;  // 2 waves (half 0/1) per row
    const int row = blockIdx.x * 4 + r;
    // stage MLP weights (transposed, PADDED) while refine's table scan runs
    for (int t = tid; t < 2048; t += 512) { int o = t >> 6, k = t & 63; W2T[k * 33 + o] = W2[t]; }
    for (int t = tid; t < 1024; t += 512) { int o = t >> 5, k = t & 31; W3T[k * 33 + o] = W3[t]; }
    for (int t = tid; t < 1024; t += 512) { int o = t >> 5, k = t & 31; D1T[k * 33 + o] = D1[t]; }
    for (int t = tid; t < 2048; t += 512) { int o = t >> 5, k = t & 31; D2T[k * 65 + o] = D2[t]; }
    if (tid < 32) b2f[tid] = b2[tid];
    else if (tid < 64) b3f[tid - 32] = b3[tid - 32];
    else if (tid < 96) d1f[tid - 64] = d1[tid - 64];
    else if (tid < 160) d2f[tid - 96] = d2[tid - 96];
    if (tid < 4) { ccnt[tid] = 0; rowbest[tid] = 0xFFFFFFFFu; }
    __syncthreads();

    // ---- refine: split table scan (each wave-half scans stride-128) ----
    unsigned int vals[4];
    int nv = 0;
    unsigned int best = 0xFFFFFFFFu;
    for (int i = half * 64 + lane; i < NSLOT * 2; i += 128) {
        const unsigned int v = rowtab[(size_t)row * NSLOT * 2 + i];
        vals[nv++] = v;
        best = minu(best, v);
    }
#pragma unroll
    for (int d = 1; d < 64; d <<= 1) best = minu(best, __shfl_xor(best, d));
    if (lane == 0) atomicMin(&rowbest[r], best);
    __syncthreads();
    best = rowbest[r];

    const float dmin = unfkey(best & KMASK);
    const unsigned int tkey = fkey(dmin + 5.0f);
    for (int k = 0; k < nv; ++k)
        if ((vals[k] & KMASK) < tkey) {
            const int p = atomicAdd(&ccnt[r], 1);
            if (p < 64) clist[r][p] = vals[k] & 8191u;
        }
    __syncthreads();
    int cnt = ccnt[r];
    cnt = cnt > 64 ? 64 : cnt;

    // ---- exact distances: 2-wave parity split + depth-1 prefetch ----
    const float4* xi = (const float4*)(xs + (size_t)row * DIM);
    const float4 x0 = xi[2 * lane], x1 = xi[2 * lane + 1];
    const float sqi = sq[row];
    const int g8 = lane >> 3;
    float4 cy0 = {0.f, 0.f, 0.f, 0.f}, cy1 = {0.f, 0.f, 0.f, 0.f};
    if (half < cnt) {
        const float4* xj = (const float4*)(xs + (size_t)clist[r][half] * DIM);
        cy0 = xj[2 * lane];
        cy1 = xj[2 * lane + 1];
    }
    for (int c = half; c < cnt; c += 2) {
        float4 ny0 = {0.f, 0.f, 0.f, 0.f}, ny1 = {0.f, 0.f, 0.f, 0.f};
        const int cn = c + 2;
        if (cn < cnt) {  // issue next-candidate load before current compute
            const float4* xj = (const float4*)(xs + (size_t)clist[r][cn] * DIM);
            ny0 = xj[2 * lane];
            ny1 = xj[2 * lane + 1];
        }
        float dot = 0.f;
        dot = fmaf(x0.x, cy0.x, dot); dot = fmaf(x0.y, cy0.y, dot);
        dot = fmaf(x0.z, cy0.z, dot); dot = fmaf(x0.w, cy0.w, dot);
        dot = fmaf(x1.x, cy1.x, dot); dot = fmaf(x1.y, cy1.y, dot);
        dot = fmaf(x1.z, cy1.z, dot); dot = fmaf(x1.w, cy1.w, dot);
        dot += __shfl_xor(dot, 1);
        dot += __shfl_xor(dot, 2);
        dot += __shfl_xor(dot, 4);
        if ((lane & 7) == 0) pbuf[r][c * 8 + g8] = dot;
        cy0 = ny0;
        cy1 = ny1;
    }
    __syncthreads();  // cross-wave pbuf visibility

    // ---- batch gather + single min-reduce (half-0 wave only) ----
    if (half == 0) {
        unsigned long long key = ~0ull;
        if (lane < cnt) {
            const unsigned int j = clist[r][lane];
            float dot = 0.f;
#pragma unroll
            for (int k = 0; k < 8; ++k)
                dot += pbuf[r][lane * 8 + ((k + lane + (lane >> 3)) & 7)];
            const float d2v = sqi + sq[j] - 2.f * dot;
            key = (((unsigned long long)fkey(d2v)) << 32) | j;
        }
#pragma unroll
        for (int d = 1; d < 64; d <<= 1) key = min64(key, __shfl_xor(key, d));
        if (lane == 0) nnr_s[r] = (unsigned int)(key & 0xFFFFFFFFull) & 8191u;
    }
    __syncthreads();
    if (half == 1) return;  // no barriers past this point
    const unsigned int nnr = nnr_s[r];

    // ---- mid (readlane broadcasts; dual-accumulator ILP) ----
    const int o32 = lane & 31;
    const float b1v = b1[lane];
    const float pr = P[(size_t)row * 64 + lane];
    const float p0 = P[(size_t)nnr * 64 + lane];
    const float a1 = p0 + b1v;
    const float u1 = pr - p0;
    const float h1 = fmaxf(a1, 0.f);
    const float th1 = (a1 > 0.f) ? u1 : 0.f;
    float a2a = b2f[o32], a2b = 0.f, u2a = 0.f, u2b = 0.f;
#pragma unroll
    for (int k = 0; k < 64; k += 2) {
        const float ha = bcastf(h1, k), hb = bcastf(h1, k + 1);
        const float ta = bcastf(th1, k), tb = bcastf(th1, k + 1);
        const float wa = W2T[k * 33 + o32], wb = W2T[(k + 1) * 33 + o32];
        a2a = fmaf(ha, wa, a2a);
        a2b = fmaf(hb, wb, a2b);
        u2a = fmaf(ta, wa, u2a);
        u2b = fmaf(tb, wb, u2b);
    }
    const float a2 = a2a + a2b;
    const float u2 = u2a + u2b;
    const float sv = fmaxf(a2, 0.f) + ((a2 > 0.f) ? u2 : 0.f);
    float za = b3f[o32], zb = 0.f;
#pragma unroll
    for (int k = 0; k < 32; k += 2) {
        za = fmaf(bcastf(sv, k), W3T[k * 33 + o32], za);
        zb = fmaf(bcastf(sv, k + 1), W3T[(k + 1) * 33 + o32], zb);
    }
    const float z = za + zb;
    if (lane < 32) out_zs[(size_t)row * 32 + lane] = z;
    float g1a = d1f[o32], g1b = 0.f;
#pragma unroll
    for (int k = 0; k < 32; k += 2) {
        g1a = fmaf(bcastf(z, k), D1T[k * 33 + o32], g1a);
        g1b = fmaf(bcastf(z, k + 1), D1T[(k + 1) * 33 + o32], g1b);
    }
    const float g1 = fmaxf(g1a + g1b, 0.f);
    float g2a = d2f[lane], g2b = 0.f;
#pragma unroll
    for (int k = 0; k < 32; k += 2) {
        g2a = fmaf(bcastf(g1, k), D2T[k * 65 + lane], g2a);
        g2b = fmaf(bcastf(g1, k + 1), D2T[(k + 1) * 65 + lane], g2b);
    }
    const float g2 = fmaxf(g2a + g2b, 0.f);
    G2[(size_t)row * 64 + lane] = g2;
}

// ---------------------------------------------------------------- k_dec
// 512 threads / 8 waves: per-wave 64x32 tile. Same math, same grid.
__global__ __launch_bounds__(512) void k_dec(const float* __restrict__ G2,
                                             const float* __restrict__ D3,
                                             const float* __restrict__ d3,
                                             float* __restrict__ xhat) {
    __shared__ __align__(16) unsigned short lGh[128 * 64], lGl[128 * 64];
    __shared__ __align__(16) unsigned short lDh[128 * 64], lDl[128 * 64];
    const int tid = threadIdx.x, wave = tid >> 6, lane = tid & 63, quad = lane >> 4,
              ln = lane & 15;
    const int i0 = blockIdx.x * 128, nbase = blockIdx.y * 128;
    const int m_off = (wave & 1) * 64, n_off = (wave >> 1) * 32;
#pragma unroll
    for (int r = 0; r < 2; ++r) {
        const int g = r * 512 + tid;
        const int row = g >> 3, cIdx = g & 7, half = cIdx >> 2, cc = cIdx & 3;
        const int wofs = row * 64 + half * 32 + ((cc + (row >> 1)) & 3) * 8;
        {
            const float* src = G2 + (size_t)(i0 + row) * 64 + cIdx * 8;
            const float4 f0 = *(const float4*)src, f1 = *(const float4*)(src + 4);
            float v[8] = {f0.x, f0.y, f0.z, f0.w, f1.x, f1.y, f1.z, f1.w};
            u16x8 h8, l8;
            split2(v, h8, l8);
            *(u16x8*)(lGh + wofs) = h8;
            *(u16x8*)(lGl + wofs) = l8;
        }
        {
            const float* src = D3 + (size_t)(nbase + row) * 64 + cIdx * 8;
            const float4 f0 = *(const float4*)src, f1 = *(const float4*)(src + 4);
            float v[8] = {f0.x, f0.y, f0.z, f0.w, f1.x, f1.y, f1.z, f1.w};
            u16x8 h8, l8;
            split2(v, h8, l8);
            *(u16x8*)(lDh + wofs) = h8;
            *(u16x8*)(lDl + wofs) = l8;
        }
    }
    __syncthreads();
    f32x4 acc[4][2];
#pragma unroll
    for (int a = 0; a < 4; ++a)
#pragma unroll
        for (int c = 0; c < 2; ++c) acc[a][c] = (f32x4){0.f, 0.f, 0.f, 0.f};
#pragma unroll
    for (int kk = 0; kk < 2; ++kk) {
        bf16x8 ah[4], al[4], bh[2], bl[2];
#pragma unroll
        for (int ms = 0; ms < 4; ++ms) {
            const int ar = m_off + ms * 16 + ln;
            const int aofs = ar * 64 + kk * 32 + ((quad + (ar >> 1)) & 3) * 8;
            ah[ms] = *(const bf16x8*)(lGh + aofs);
            al[ms] = *(const bf16x8*)(lGl + aofs);
        }
#pragma unroll
        for (int ns = 0; ns < 2; ++ns) {
            const int br = n_off + ns * 16 + ln;
            const int bofs = br * 64 + kk * 32 + ((quad + (br >> 1)) & 3) * 8;
            bh[ns] = *(const bf16x8*)(lDh + bofs);
            bl[ns] = *(const bf16x8*)(lDl + bofs);
        }
#pragma unroll
        for (int ms = 0; ms < 4; ++ms)
#pragma unroll
            for (int ns = 0; ns < 2; ++ns) {
                acc[ms][ns] = __builtin_amdgcn_mfma_f32_16x16x32_bf16(
                    ah[ms], bh[ns], acc[ms][ns], 0, 0, 0);
                acc[ms][ns] = __builtin_amdgcn_mfma_f32_16x16x32_bf16(
                    ah[ms], bl[ns], acc[ms][ns], 0, 0, 0);
                acc[ms][ns] = __builtin_amdgcn_mfma_f32_16x16x32_bf16(
                    al[ms], bh[ns], acc[ms][ns], 0, 0, 0);
            }
    }
    float d3f[2];
#pragma unroll
    for (int ns = 0; ns < 2; ++ns) d3f[ns] = d3[nbase + n_off + ns * 16 + ln];
#pragma unroll
    for (int ms = 0; ms < 4; ++ms)
#pragma unroll
        for (int ns = 0; ns < 2; ++ns)
#pragma unroll
            for (int v = 0; v < 4; ++v) {
                const int m = m_off + ms * 16 + quad * 4 + v;
                const int n = n_off + ns * 16 + ln;
                xhat[(size_t)(i0 + m) * DIM + nbase + n] = acc[ms][ns][v] + d3f[ns];
            }
}

extern "C" void kernel_launch(void* const* d_in, const int* in_sizes, int n_in,
                              void* d_out, int out_size, void* d_ws, size_t ws_size,
                              hipStream_t stream) {
    const float* xs = (const float*)d_in[0];
    const float* W1 = (const float*)d_in[1];
    const float* b1 = (const float*)d_in[2];
    const float* W2 = (const float*)d_in[3];
    const float* b2 = (const float*)d_in[4];
    const float* W3 = (const float*)d_in[5];
    const float* b3 = (const float*)d_in[6];
    const float* D1 = (const float*)d_in[7];
    const float* d1 = (const float*)d_in[8];
    const float* D2 = (const float*)d_in[9];
    const float* d2 = (const float*)d_in[10];
    const float* D3 = (const float*)d_in[11];
    const float* d3 = (const float*)d_in[12];

    // ws: sq(32K) | gap | xs_i8 (4 MB) | P | G2   (proven layout)
    char* ws = (char*)d_ws;
    float* sq = (float*)(ws);                                     // 32 KB
    unsigned char* xs_i8 = (unsigned char*)(ws + 131072);         // 4 MB
    float* P = (float*)(ws + 8519680);                            // 2 MB
    float* G2 = (float*)(ws + 10616832);                          // 2 MB

    float* xhat = (float*)d_out;
    float* zs = (float*)d_out + (size_t)NROWS * DIM;
    // rowtab scratch (u32, 8192*194*2*4 = 12.7 MB) lives in d_out's dead space
    unsigned int* rowtab = (unsigned int*)d_out;

    hipLaunchKernelGGL(k_prep, dim3(2048), dim3(256), 0, stream, xs, xs_i8, sq);
    hipLaunchKernelGGL(k_nn, dim3(2240), dim3(512), 0, stream, xs_i8, sq, rowtab, xs,
                       W1, P);
    hipLaunchKernelGGL(k_refine_mid, dim3(2048), dim3(512), 0, stream, rowtab, xs, sq,
                       P, b1, W2, b2, W3, b3, D1, d1, D2, d2, zs, G2);
    hipLaunchKernelGGL(k_dec, dim3(64, 4), dim3(512), 0, stream, G2, D3, d3, xhat);
}

// Round 13
// 156.222 us; speedup vs baseline: 1.4335x; 1.0402x over previous
//
#include <hip/hip_runtime.h>
#include <hip/hip_bf16.h>

#define NROWS 8192
#define DIM 512
#define NSLOT 194  // per-row top-2 slots: 66 row-side + 128 col-side (32 s x 4 row-groups)
#define KMASK 0xFFFFE000u  // top-19 key bits; low 13 = index
#define QSCALE 21.0f       // i8 quantization scale: clamp +-6.05 (> global max ~5.2)
#define QD2 (-2.0f / (QSCALE * QSCALE))

typedef __attribute__((ext_vector_type(8))) short bf16x8;
typedef __attribute__((ext_vector_type(4))) float f32x4;
typedef __attribute__((ext_vector_type(4))) int i32x4;
typedef __attribute__((ext_vector_type(8))) unsigned short u16x8;

__device__ __forceinline__ float bf2f(unsigned short u) {
    return __uint_as_float(((unsigned int)u) << 16);
}
__device__ __forceinline__ unsigned short f2bf(float f) {
    unsigned int b = __float_as_uint(f);
    return (unsigned short)((b + 0x7FFFu + ((b >> 16) & 1u)) >> 16);
}
// fp32 -> signed i8, RNE, scale QSCALE (no clipping for N(0,1): 127/21=6.05 > max ~5.2)
__device__ __forceinline__ unsigned char f2i8(float x) {
    float s = x * QSCALE;
    s = fminf(fmaxf(s, -127.f), 127.f);
    const int q = __float2int_rn(s);
    return (unsigned char)(q & 0xFF);
}
// monotone float->uint key
__device__ __forceinline__ unsigned int fkey(float f) {
    unsigned int b = __float_as_uint(f);
    return (b & 0x80000000u) ? ~b : (b | 0x80000000u);
}
__device__ __forceinline__ float unfkey(unsigned int u) {
    unsigned int b = (u & 0x80000000u) ? (u ^ 0x80000000u) : ~u;
    return __uint_as_float(b);
}
__device__ __forceinline__ unsigned int minu(unsigned int a, unsigned int b) {
    return a < b ? a : b;
}
__device__ __forceinline__ unsigned int maxu(unsigned int a, unsigned int b) {
    return a > b ? a : b;
}
__device__ __forceinline__ unsigned long long min64(unsigned long long a,
                                                    unsigned long long b) {
    return a < b ? a : b;
}
// VALU-pipe lane broadcast (v_readlane, compile-time k) -- r7-proven DS-pipe fix.
__device__ __forceinline__ float bcastf(float v, int k) {
    return __uint_as_float((unsigned int)__builtin_amdgcn_readlane(__float_as_uint(v), k));
}

// helper: 3-way bf16 split
__device__ __forceinline__ void split3(const float* v, u16x8& h8, u16x8& m8, u16x8& l8) {
#pragma unroll
    for (int j = 0; j < 8; ++j) {
        const float x = v[j];
        const unsigned short h = f2bf(x);
        const float r1 = x - bf2f(h);
        const unsigned short m = f2bf(r1);
        const float r2 = r1 - bf2f(m);
        h8[j] = h; m8[j] = m; l8[j] = f2bf(r2);
    }
}
// helper: 2-way split
__device__ __forceinline__ void split2(const float* v, u16x8& h8, u16x8& l8) {
#pragma unroll
    for (int j = 0; j < 8; ++j) {
        const float x = v[j];
        const unsigned short h = f2bf(x);
        h8[j] = h; l8[j] = f2bf(x - bf2f(h));
    }
}

// ---------------------------------------------------------------- k_prep
// Prep ONLY (i8 plane + sq): 2048 blocks, HBM-bound (~20 MB traffic).
__global__ __launch_bounds__(256) void k_prep(const float* __restrict__ xs,
                                              unsigned char* __restrict__ x8,
                                              float* __restrict__ sq) {
    const int tid = threadIdx.x;
    const int wave = tid >> 6, lane = tid & 63;
    const int row = blockIdx.x * 4 + wave;
    const float4* xr = (const float4*)(xs + (size_t)row * DIM);
    const float4 a = xr[2 * lane], b = xr[2 * lane + 1];
    float v[8] = {a.x, a.y, a.z, a.w, b.x, b.y, b.z, b.w};
    unsigned long long pk8 = 0ull;
    float s = 0.f;
#pragma unroll
    for (int i = 0; i < 8; ++i) {
        pk8 |= ((unsigned long long)f2i8(v[i])) << (8 * i);
        s = fmaf(v[i], v[i], s);
    }
    *(unsigned long long*)(x8 + (size_t)row * DIM + lane * 8) = pk8;
#pragma unroll
    for (int d = 32; d; d >>= 1) s += __shfl_xor(s, d);
    if (lane == 0) sq[row] = s;
}

// ---------------------------------------------------------------- k_nn
// EXACT r10 configuration (session best, 156.6 us wall): launch_bounds(512,4),
// LDS double-buffer + DMA + pair swizzle. Occupancy triptych settled by
// measurement: 2 blocks/CU + perfect coalescing (r10, 44us) beats 4 blocks/CU
// (r12, 47us + 2.4x HBM from L2 thrash) and beats no-LDS direct-L2 fragments
// (r11, 110us from 16-line address divergence on the TA pipe).
// Blocks 0..127: P = xs @ W1^T (tid<256 guard). Blocks 128..2239: i8 nn.
__global__ __launch_bounds__(512, 4) void k_nn(const unsigned char* __restrict__ x8,
                                               const float* __restrict__ sq,
                                               unsigned int* __restrict__ rowtab,
                                               const float* __restrict__ xs,
                                               const float* __restrict__ W1,
                                               float* __restrict__ P) {
    __shared__ __align__(16) unsigned char lsm[32768];
    const int tid = threadIdx.x;
    const int wave = tid >> 6, lane = tid & 63, quad = lane >> 4, ln = lane & 15;

    if (blockIdx.x < 128) {
        // ---- P-GEMM tile (256 active threads; all 512 hit barriers) ----
        unsigned short* lAh = (unsigned short*)(lsm);
        unsigned short* lAm = (unsigned short*)(lsm + 4096);
        unsigned short* lAl = (unsigned short*)(lsm + 8192);
        unsigned short* lWh = (unsigned short*)(lsm + 12288);
        unsigned short* lWm = (unsigned short*)(lsm + 16384);
        unsigned short* lWl = (unsigned short*)(lsm + 20480);
        const int i0 = blockIdx.x * 64;
        const int row = tid >> 2, c = tid & 3;
        const int wofs = row * 32 + ((c + (row >> 1)) & 3) * 8;
        f32x4 acc[4];
#pragma unroll
        for (int ns = 0; ns < 4; ++ns) acc[ns] = (f32x4){0.f, 0.f, 0.f, 0.f};
        const int ar = wave * 16 + ln;
        const int aofs = ar * 32 + ((quad + (ar >> 1)) & 3) * 8;
        int bofs[4];
#pragma unroll
        for (int ns = 0; ns < 4; ++ns) {
            const int br = ns * 16 + ln;
            bofs[ns] = br * 32 + ((quad + (br >> 1)) & 3) * 8;
        }
        for (int kt = 0; kt < 16; ++kt) {
            __syncthreads();
            if (tid < 256) {
                {
                    const float* src = xs + (size_t)(i0 + row) * DIM + kt * 32 + c * 8;
                    const float4 f0 = *(const float4*)src, f1 = *(const float4*)(src + 4);
                    float v[8] = {f0.x, f0.y, f0.z, f0.w, f1.x, f1.y, f1.z, f1.w};
                    u16x8 h8, m8, l8;
                    split3(v, h8, m8, l8);
                    *(u16x8*)(lAh + wofs) = h8;
                    *(u16x8*)(lAm + wofs) = m8;
                    *(u16x8*)(lAl + wofs) = l8;
                }
                {
                    const float* src = W1 + (size_t)row * DIM + kt * 32 + c * 8;
                    const float4 f0 = *(const float4*)src, f1 = *(const float4*)(src + 4);
                    float v[8] = {f0.x, f0.y, f0.z, f0.w, f1.x, f1.y, f1.z, f1.w};
                    u16x8 h8, m8, l8;
                    split3(v, h8, m8, l8);
                    *(u16x8*)(lWh + wofs) = h8;
                    *(u16x8*)(lWm + wofs) = m8;
                    *(u16x8*)(lWl + wofs) = l8;
                }
            }
            __syncthreads();
            if (tid < 256) {
                const bf16x8 ah = *(const bf16x8*)(lAh + aofs);
                const bf16x8 am = *(const bf16x8*)(lAm + aofs);
                const bf16x8 al = *(const bf16x8*)(lAl + aofs);
#pragma unroll
                for (int ns = 0; ns < 4; ++ns) {
                    const bf16x8 bh = *(const bf16x8*)(lWh + bofs[ns]);
                    const bf16x8 bm = *(const bf16x8*)(lWm + bofs[ns]);
                    const bf16x8 bl = *(const bf16x8*)(lWl + bofs[ns]);
                    acc[ns] = __builtin_amdgcn_mfma_f32_16x16x32_bf16(ah, bh, acc[ns], 0, 0, 0);
                    acc[ns] = __builtin_amdgcn_mfma_f32_16x16x32_bf16(ah, bm, acc[ns], 0, 0, 0);
                    acc[ns] = __builtin_amdgcn_mfma_f32_16x16x32_bf16(am, bh, acc[ns], 0, 0, 0);
                    acc[ns] = __builtin_amdgcn_mfma_f32_16x16x32_bf16(am, bm, acc[ns], 0, 0, 0);
                    acc[ns] = __builtin_amdgcn_mfma_f32_16x16x32_bf16(ah, bl, acc[ns], 0, 0, 0);
                    acc[ns] = __builtin_amdgcn_mfma_f32_16x16x32_bf16(al, bh, acc[ns], 0, 0, 0);
                }
            }
        }
        if (tid < 256) {
#pragma unroll
            for (int ns = 0; ns < 4; ++ns)
#pragma unroll
                for (int v = 0; v < 4; ++v)
                    P[(size_t)(i0 + wave * 16 + quad * 4 + v) * 64 + ns * 16 + ln] =
                        acc[ns][v];
        }
        return;
    }

    // ---- i8 nn body (r10-proven: LDS double-buffer + DMA + pair swizzle) ----
    unsigned char* lA = lsm;            // A tiles: 2 x 8192
    unsigned char* lB = lsm + 16384;    // B tiles: 2 x 8192
    const int b = blockIdx.x - 128;
    const int xcd = b & 7, w = b >> 3;
    const int s = w >> 3, bil = w & 7;
    const int bi = xcd * 8 + bil;
    const int bj = (bi + s) & 63;
    const int i0 = bi * 128, j0 = bj * 128;
    const int m_off = (wave >> 1) * 32, n_off = (wave & 1) * 64;

    const int rl = lane >> 2;
    const int sp = ((lane & 3) - ((rl >> 1) & 3)) & 3;
    const unsigned char* gpA = x8 + (size_t)(i0 + wave * 16 + rl) * DIM + sp * 16;
    const unsigned char* gpB = x8 + (size_t)(j0 + wave * 16 + rl) * DIM + sp * 16;
    unsigned char* dstA = lA + wave * 1024;
    unsigned char* dstB = lB + wave * 1024;

    // K=64 fragment: one b128 per (ms)/(ns) -- pair quad at swizzled pos
    int aoff[2], boff[4];
#pragma unroll
    for (int ms = 0; ms < 2; ++ms) {
        const int r = m_off + ms * 16 + ln;
        aoff[ms] = r * 64 + ((quad + ((r >> 1) & 3)) & 3) * 16;
    }
#pragma unroll
    for (int ns = 0; ns < 4; ++ns) {
        const int r = n_off + ns * 16 + ln;
        boff[ns] = r * 64 + ((quad + ((r >> 1) & 3)) & 3) * 16;
    }

    i32x4 acc[2][4];
#pragma unroll
    for (int a = 0; a < 2; ++a)
#pragma unroll
        for (int c = 0; c < 4; ++c) acc[a][c] = (i32x4){0, 0, 0, 0};

    __builtin_amdgcn_global_load_lds(
        (const __attribute__((address_space(1))) void*)gpA,
        (__attribute__((address_space(3))) void*)dstA, 16, 0, 0);
    __builtin_amdgcn_global_load_lds(
        (const __attribute__((address_space(1))) void*)gpB,
        (__attribute__((address_space(3))) void*)dstB, 16, 0, 0);

#pragma unroll
    for (int kt = 0; kt < 8; ++kt) {
        __syncthreads();  // drains DMA filling buf[kt&1]; prior reads done
        if (kt < 7) {
            const int nxt = ((kt + 1) & 1) * 8192;
            __builtin_amdgcn_global_load_lds(
                (const __attribute__((address_space(1))) void*)(gpA + (kt + 1) * 64),
                (__attribute__((address_space(3))) void*)(dstA + nxt), 16, 0, 0);
            __builtin_amdgcn_global_load_lds(
                (const __attribute__((address_space(1))) void*)(gpB + (kt + 1) * 64),
                (__attribute__((address_space(3))) void*)(dstB + nxt), 16, 0, 0);
        }
        const int cur = (kt & 1) * 8192;
        i32x4 av[2], bv[4];
#pragma unroll
        for (int ms = 0; ms < 2; ++ms)
            av[ms] = *(const i32x4*)(lA + cur + aoff[ms]);
#pragma unroll
        for (int ns = 0; ns < 4; ++ns)
            bv[ns] = *(const i32x4*)(lB + cur + boff[ns]);
#pragma unroll
        for (int ms = 0; ms < 2; ++ms)
#pragma unroll
            for (int ns = 0; ns < 4; ++ns)
                acc[ms][ns] = __builtin_amdgcn_mfma_i32_16x16x64_i8(
                    av[ms], bv[ns], acc[ms][ns], 0, 0, 0);
    }
    __syncthreads();  // all waves done reading lA/lB -> safe to reuse as rowbuf

    // ---- epilogue: full-d2 u32 keys; row-side LDS-transpose top-2 ----
    const bool diag = (s == 0);
    float sqj[4];
#pragma unroll
    for (int ns = 0; ns < 4; ++ns) sqj[ns] = sq[j0 + n_off + ns * 16 + ln];
    float sqi[2][4];
#pragma unroll
    for (int ms = 0; ms < 2; ++ms)
#pragma unroll
        for (int v = 0; v < 4; ++v)
            sqi[ms][v] = sq[i0 + m_off + ms * 16 + quad * 4 + v];

    unsigned long long* rowbuf = (unsigned long long*)(void*)lsm + (size_t)wave * 512;

    unsigned int c1[4], c2[4];
#pragma unroll
    for (int ns = 0; ns < 4; ++ns) { c1[ns] = 0xFFFFFFFFu; c2[ns] = 0xFFFFFFFFu; }

#pragma unroll
    for (int ms = 0; ms < 2; ++ms)
#pragma unroll
        for (int v = 0; v < 4; ++v) {
            const int gi = i0 + m_off + ms * 16 + quad * 4 + v;
            const float si = sqi[ms][v];
            unsigned int rp[4];
#pragma unroll
            for (int ns = 0; ns < 4; ++ns) {
                const int gj = j0 + n_off + ns * 16 + ln;
                float d2 = fmaf((float)acc[ms][ns][v], QD2, si + sqj[ns]);
                if (diag && gj == gi) d2 = __builtin_inff();
                const unsigned int ub = (__float_as_uint(d2) | 0x80000000u) & KMASK;
                rp[ns] = ub | (unsigned int)gj;
                const unsigned int cp = ub | (unsigned int)gi;
                c2[ns] = minu(c2[ns], maxu(c1[ns], cp));
                c1[ns] = minu(c1[ns], cp);
            }
            const unsigned int lo1 = minu(rp[0], rp[1]), hi1 = maxu(rp[0], rp[1]);
            const unsigned int lo2 = minu(rp[2], rp[3]), hi2 = maxu(rp[2], rp[3]);
            const unsigned int p1 = minu(lo1, lo2);
            const unsigned int p2 = minu(maxu(lo1, lo2), minu(hi1, hi2));
            const int rloc = ms * 16 + quad * 4 + v;
            rowbuf[rloc * 16 + ln] = (((unsigned long long)p1) << 32) | p2;
        }
    asm volatile("s_waitcnt lgkmcnt(0)" ::: "memory");  // same-wave write->read order

    {
        const int rr = lane & 31, hf = lane >> 5;
        unsigned int p1 = 0xFFFFFFFFu, p2 = 0xFFFFFFFFu;
#pragma unroll
        for (int k = 0; k < 8; ++k) {
            const int pos = hf * 8 + (k ^ (rr & 7));
            const unsigned long long pw = rowbuf[rr * 16 + pos];
            const unsigned int a1 = (unsigned int)(pw >> 32), a2 = (unsigned int)pw;
            p2 = minu(minu(p2, a2), maxu(p1, a1));
            p1 = minu(p1, a1);
        }
        const unsigned long long mine = (((unsigned long long)p1) << 32) | p2;
        const unsigned long long oth = __shfl_xor(mine, 32);
        {
            const unsigned int a1 = (unsigned int)(oth >> 32), a2 = (unsigned int)oth;
            p2 = minu(minu(p2, a2), maxu(p1, a1));
            p1 = minu(p1, a1);
        }
        if (lane < 32) {
            const int gi = i0 + m_off + rr;
            const size_t base = ((size_t)gi * NSLOT + (s * 2 + (wave & 1))) * 2;
            rowtab[base] = p1;
            rowtab[base + 1] = p2;
        }
    }

    if (s > 0) {
#pragma unroll
        for (int ns = 0; ns < 4; ++ns) {
            unsigned int q1 = c1[ns], q2 = c2[ns];
#pragma unroll
            for (int d = 16; d <= 32; d <<= 1) {
                const unsigned long long pr = (((unsigned long long)q1) << 32) | q2;
                const unsigned long long o = __shfl_xor(pr, d);
                const unsigned int a1 = (unsigned int)(o >> 32), a2 = (unsigned int)o;
                q2 = minu(minu(q2, a2), maxu(q1, a1));
                q1 = minu(q1, a1);
            }
            if (lane < 16) {
                const int gj = j0 + n_off + ns * 16 + ln;
                const size_t base =
                    ((size_t)gj * NSLOT + (66 + (s - 1) * 4 + (wave >> 1))) * 2;
                rowtab[base] = q1;
                rowtab[base + 1] = q2;
            }
        }
    }
}

// ---------------------------------------------------------------- k_refine_mid
// FUSED refine + mid (r7/r9/r10-proven: padded weight LDS, readlane
// broadcasts, i8 margin 5, dual-accumulator MLP chains).
__global__ __launch_bounds__(512, 6) void k_refine_mid(
    const unsigned int* __restrict__ rowtab, const float* __restrict__ xs,
    const float* __restrict__ sq, const float* __restrict__ P,
    const float* __restrict__ b1, const float* __restrict__ W2,
    const float* __restrict__ b2, const float* __restrict__ W3,
    const float* __restrict__ b3, const float* __restrict__ D1,
    const float* __restrict__ d1, const float* __restrict__ D2,
    const float* __restrict__ d2, float* __restrict__ out_zs,
    float* __restrict__ G2) {
    __shared__ float W2T[64 * 33], W3T[32 * 33], D1T[32 * 33], D2T[32 * 65];
    __shared__ float b2f[32], b3f[32], d1f[32], d2f[64];
    __shared__ unsigned int clist[4][64];
    __shared__ int ccnt[4];
    __shared__ unsigned int rowbest[4];
    __shared__ unsigned int nnr_s[4];
    __shared__ float pbuf[4][64 * 8];  // [row-in-block][cand*8 + group8]
    const int tid = threadIdx.x;
    const int wave = tid >> 6, lane = tid & 63;
    const int r = wave & 3, half = wave >> 2;  // 2 waves (half 0/1) per row
    const int row = blockIdx.x * 4 + r;
    // stage MLP weights (transposed, PADDED) while refine's table scan runs
    for (int t = tid; t < 2048; t += 512) { int o = t >> 6, k = t & 63; W2T[k * 33 + o] = W2[t]; }
    for (int t = tid; t < 1024; t += 512) { int o = t >> 5, k = t & 31; W3T[k * 33 + o] = W3[t]; }
    for (int t = tid; t < 1024; t += 512) { int o = t >> 5, k = t & 31; D1T[k * 33 + o] = D1[t]; }
    for (int t = tid; t < 2048; t += 512) { int o = t >> 5, k = t & 31; D2T[k * 65 + o] = D2[t]; }
    if (tid < 32) b2f[tid] = b2[tid];
    else if (tid < 64) b3f[tid - 32] = b3[tid - 32];
    else if (tid < 96) d1f[tid - 64] = d1[tid - 64];
    else if (tid < 160) d2f[tid - 96] = d2[tid - 96];
    if (tid < 4) { ccnt[tid] = 0; rowbest[tid] = 0xFFFFFFFFu; }
    __syncthreads();

    // ---- refine: split table scan (each wave-half scans stride-128) ----
    unsigned int vals[4];
    int nv = 0;
    unsigned int best = 0xFFFFFFFFu;
    for (int i = half * 64 + lane; i < NSLOT * 2; i += 128) {
        const unsigned int v = rowtab[(size_t)row * NSLOT * 2 + i];
        vals[nv++] = v;
        best = minu(best, v);
    }
#pragma unroll
    for (int d = 1; d < 64; d <<= 1) best = minu(best, __shfl_xor(best, d));
    if (lane == 0) atomicMin(&rowbest[r], best);
    __syncthreads();
    best = rowbest[r];

    const float dmin = unfkey(best & KMASK);
    const unsigned int tkey = fkey(dmin + 5.0f);
    for (int k = 0; k < nv; ++k)
        if ((vals[k] & KMASK) < tkey) {
            const int p = atomicAdd(&ccnt[r], 1);
            if (p < 64) clist[r][p] = vals[k] & 8191u;
        }
    __syncthreads();
    int cnt = ccnt[r];
    cnt = cnt > 64 ? 64 : cnt;

    // ---- exact distances: 2-wave parity split + depth-1 prefetch ----
    const float4* xi = (const float4*)(xs + (size_t)row * DIM);
    const float4 x0 = xi[2 * lane], x1 = xi[2 * lane + 1];
    const float sqi = sq[row];
    const int g8 = lane >> 3;
    float4 cy0 = {0.f, 0.f, 0.f, 0.f}, cy1 = {0.f, 0.f, 0.f, 0.f};
    if (half < cnt) {
        const float4* xj = (const float4*)(xs + (size_t)clist[r][half] * DIM);
        cy0 = xj[2 * lane];
        cy1 = xj[2 * lane + 1];
    }
    for (int c = half; c < cnt; c += 2) {
        float4 ny0 = {0.f, 0.f, 0.f, 0.f}, ny1 = {0.f, 0.f, 0.f, 0.f};
        const int cn = c + 2;
        if (cn < cnt) {  // issue next-candidate load before current compute
            const float4* xj = (const float4*)(xs + (size_t)clist[r][cn] * DIM);
            ny0 = xj[2 * lane];
            ny1 = xj[2 * lane + 1];
        }
        float dot = 0.f;
        dot = fmaf(x0.x, cy0.x, dot); dot = fmaf(x0.y, cy0.y, dot);
        dot = fmaf(x0.z, cy0.z, dot); dot = fmaf(x0.w, cy0.w, dot);
        dot = fmaf(x1.x, cy1.x, dot); dot = fmaf(x1.y, cy1.y, dot);
        dot = fmaf(x1.z, cy1.z, dot); dot = fmaf(x1.w, cy1.w, dot);
        dot += __shfl_xor(dot, 1);
        dot += __shfl_xor(dot, 2);
        dot += __shfl_xor(dot, 4);
        if ((lane & 7) == 0) pbuf[r][c * 8 + g8] = dot;
        cy0 = ny0;
        cy1 = ny1;
    }
    __syncthreads();  // cross-wave pbuf visibility

    // ---- batch gather + single min-reduce (half-0 wave only) ----
    if (half == 0) {
        unsigned long long key = ~0ull;
        if (lane < cnt) {
            const unsigned int j = clist[r][lane];
            float dot = 0.f;
#pragma unroll
            for (int k = 0; k < 8; ++k)
                dot += pbuf[r][lane * 8 + ((k + lane + (lane >> 3)) & 7)];
            const float d2v = sqi + sq[j] - 2.f * dot;
            key = (((unsigned long long)fkey(d2v)) << 32) | j;
        }
#pragma unroll
        for (int d = 1; d < 64; d <<= 1) key = min64(key, __shfl_xor(key, d));
        if (lane == 0) nnr_s[r] = (unsigned int)(key & 0xFFFFFFFFull) & 8191u;
    }
    __syncthreads();
    if (half == 1) return;  // no barriers past this point
    const unsigned int nnr = nnr_s[r];

    // ---- mid (readlane broadcasts; dual-accumulator ILP) ----
    const int o32 = lane & 31;
    const float b1v = b1[lane];
    const float pr = P[(size_t)row * 64 + lane];
    const float p0 = P[(size_t)nnr * 64 + lane];
    const float a1 = p0 + b1v;
    const float u1 = pr - p0;
    const float h1 = fmaxf(a1, 0.f);
    const float th1 = (a1 > 0.f) ? u1 : 0.f;
    float a2a = b2f[o32], a2b = 0.f, u2a = 0.f, u2b = 0.f;
#pragma unroll
    for (int k = 0; k < 64; k += 2) {
        const float ha = bcastf(h1, k), hb = bcastf(h1, k + 1);
        const float ta = bcastf(th1, k), tb = bcastf(th1, k + 1);
        const float wa = W2T[k * 33 + o32], wb = W2T[(k + 1) * 33 + o32];
        a2a = fmaf(ha, wa, a2a);
        a2b = fmaf(hb, wb, a2b);
        u2a = fmaf(ta, wa, u2a);
        u2b = fmaf(tb, wb, u2b);
    }
    const float a2 = a2a + a2b;
    const float u2 = u2a + u2b;
    const float sv = fmaxf(a2, 0.f) + ((a2 > 0.f) ? u2 : 0.f);
    float za = b3f[o32], zb = 0.f;
#pragma unroll
    for (int k = 0; k < 32; k += 2) {
        za = fmaf(bcastf(sv, k), W3T[k * 33 + o32], za);
        zb = fmaf(bcastf(sv, k + 1), W3T[(k + 1) * 33 + o32], zb);
    }
    const float z = za + zb;
    if (lane < 32) out_zs[(size_t)row * 32 + lane] = z;
    float g1a = d1f[o32], g1b = 0.f;
#pragma unroll
    for (int k = 0; k < 32; k += 2) {
        g1a = fmaf(bcastf(z, k), D1T[k * 33 + o32], g1a);
        g1b = fmaf(bcastf(z, k + 1), D1T[(k + 1) * 33 + o32], g1b);
    }
    const float g1 = fmaxf(g1a + g1b, 0.f);
    float g2a = d2f[lane], g2b = 0.f;
#pragma unroll
    for (int k = 0; k < 32; k += 2) {
        g2a = fmaf(bcastf(g1, k), D2T[k * 65 + lane], g2a);
        g2b = fmaf(bcastf(g1, k + 1), D2T[(k + 1) * 65 + lane], g2b);
    }
    const float g2 = fmaxf(g2a + g2b, 0.f);
    G2[(size_t)row * 64 + lane] = g2;
}

// ---------------------------------------------------------------- k_dec
// 512 threads / 8 waves: per-wave 64x32 tile. Same math, same grid.
__global__ __launch_bounds__(512) void k_dec(const float* __restrict__ G2,
                                             const float* __restrict__ D3,
                                             const float* __restrict__ d3,
                                             float* __restrict__ xhat) {
    __shared__ __align__(16) unsigned short lGh[128 * 64], lGl[128 * 64];
    __shared__ __align__(16) unsigned short lDh[128 * 64], lDl[128 * 64];
    const int tid = threadIdx.x, wave = tid >> 6, lane = tid & 63, quad = lane >> 4,
              ln = lane & 15;
    const int i0 = blockIdx.x * 128, nbase = blockIdx.y * 128;
    const int m_off = (wave & 1) * 64, n_off = (wave >> 1) * 32;
#pragma unroll
    for (int r = 0; r < 2; ++r) {
        const int g = r * 512 + tid;
        const int row = g >> 3, cIdx = g & 7, half = cIdx >> 2, cc = cIdx & 3;
        const int wofs = row * 64 + half * 32 + ((cc + (row >> 1)) & 3) * 8;
        {
            const float* src = G2 + (size_t)(i0 + row) * 64 + cIdx * 8;
            const float4 f0 = *(const float4*)src, f1 = *(const float4*)(src + 4);
            float v[8] = {f0.x, f0.y, f0.z, f0.w, f1.x, f1.y, f1.z, f1.w};
            u16x8 h8, l8;
            split2(v, h8, l8);
            *(u16x8*)(lGh + wofs) = h8;
            *(u16x8*)(lGl + wofs) = l8;
        }
        {
            const float* src = D3 + (size_t)(nbase + row) * 64 + cIdx * 8;
            const float4 f0 = *(const float4*)src, f1 = *(const float4*)(src + 4);
            float v[8] = {f0.x, f0.y, f0.z, f0.w, f1.x, f1.y, f1.z, f1.w};
            u16x8 h8, l8;
            split2(v, h8, l8);
            *(u16x8*)(lDh + wofs) = h8;
            *(u16x8*)(lDl + wofs) = l8;
        }
    }
    __syncthreads();
    f32x4 acc[4][2];
#pragma unroll
    for (int a = 0; a < 4; ++a)
#pragma unroll
        for (int c = 0; c < 2; ++c) acc[a][c] = (f32x4){0.f, 0.f, 0.f, 0.f};
#pragma unroll
    for (int kk = 0; kk < 2; ++kk) {
        bf16x8 ah[4], al[4], bh[2], bl[2];
#pragma unroll
        for (int ms = 0; ms < 4; ++ms) {
            const int ar = m_off + ms * 16 + ln;
            const int aofs = ar * 64 + kk * 32 + ((quad + (ar >> 1)) & 3) * 8;
            ah[ms] = *(const bf16x8*)(lGh + aofs);
            al[ms] = *(const bf16x8*)(lGl + aofs);
        }
#pragma unroll
        for (int ns = 0; ns < 2; ++ns) {
            const int br = n_off + ns * 16 + ln;
            const int bofs = br * 64 + kk * 32 + ((quad + (br >> 1)) & 3) * 8;
            bh[ns] = *(const bf16x8*)(lDh + bofs);
            bl[ns] = *(const bf16x8*)(lDl + bofs);
        }
#pragma unroll
        for (int ms = 0; ms < 4; ++ms)
#pragma unroll
            for (int ns = 0; ns < 2; ++ns) {
                acc[ms][ns] = __builtin_amdgcn_mfma_f32_16x16x32_bf16(
                    ah[ms], bh[ns], acc[ms][ns], 0, 0, 0);
                acc[ms][ns] = __builtin_amdgcn_mfma_f32_16x16x32_bf16(
                    ah[ms], bl[ns], acc[ms][ns], 0, 0, 0);
                acc[ms][ns] = __builtin_amdgcn_mfma_f32_16x16x32_bf16(
                    al[ms], bh[ns], acc[ms][ns], 0, 0, 0);
            }
    }
    float d3f[2];
#pragma unroll
    for (int ns = 0; ns < 2; ++ns) d3f[ns] = d3[nbase + n_off + ns * 16 + ln];
#pragma unroll
    for (int ms = 0; ms < 4; ++ms)
#pragma unroll
        for (int ns = 0; ns < 2; ++ns)
#pragma unroll
            for (int v = 0; v < 4; ++v) {
                const int m = m_off + ms * 16 + quad * 4 + v;
                const int n = n_off + ns * 16 + ln;
                xhat[(size_t)(i0 + m) * DIM + nbase + n] = acc[ms][ns][v] + d3f[ns];
            }
}

extern "C" void kernel_launch(void* const* d_in, const int* in_sizes, int n_in,
                              void* d_out, int out_size, void* d_ws, size_t ws_size,
                              hipStream_t stream) {
    const float* xs = (const float*)d_in[0];
    const float* W1 = (const float*)d_in[1];
    const float* b1 = (const float*)d_in[2];
    const float* W2 = (const float*)d_in[3];
    const float* b2 = (const float*)d_in[4];
    const float* W3 = (const float*)d_in[5];
    const float* b3 = (const float*)d_in[6];
    const float* D1 = (const float*)d_in[7];
    const float* d1 = (const float*)d_in[8];
    const float* D2 = (const float*)d_in[9];
    const float* d2 = (const float*)d_in[10];
    const float* D3 = (const float*)d_in[11];
    const float* d3 = (const float*)d_in[12];

    // ws: sq(32K) | gap | xs_i8 (4 MB) | P | G2   (proven layout)
    char* ws = (char*)d_ws;
    float* sq = (float*)(ws);                                     // 32 KB
    unsigned char* xs_i8 = (unsigned char*)(ws + 131072);         // 4 MB
    float* P = (float*)(ws + 8519680);                            // 2 MB
    float* G2 = (float*)(ws + 10616832);                          // 2 MB

    float* xhat = (float*)d_out;
    float* zs = (float*)d_out + (size_t)NROWS * DIM;
    // rowtab scratch (u32, 8192*194*2*4 = 12.7 MB) lives in d_out's dead space
    unsigned int* rowtab = (unsigned int*)d_out;

    hipLaunchKernelGGL(k_prep, dim3(2048), dim3(256), 0, stream, xs, xs_i8, sq);
    hipLaunchKernelGGL(k_nn, dim3(2240), dim3(512), 0, stream, xs_i8, sq, rowtab, xs,
                       W1, P);
    hipLaunchKernelGGL(k_refine_mid, dim3(2048), dim3(512), 0, stream, rowtab, xs, sq,
                       P, b1, W2, b2, W3, b3, D1, d1, D2, d2, zs, G2);
    hipLaunchKernelGGL(k_dec, dim3(64, 4), dim3(512), 0, stream, G2, D3, d3, xhat);
}